// Round 2
// baseline (722.453 us; speedup 1.0000x reference)
//
#include <hip/hip_runtime.h>
#include <hip/hip_bf16.h>

// GCN pipeline: norm -> [agg,W1,relu] -> [W2,agg,relu] -> [W3,agg] -> LN
// Rewrites used (exact in exact arithmetic):
//   A@(x@W) = (A@x)@W  (layer1 aggregates first on 128 feats)
//   norm = dinv[src]*dinv[dst] factored: pre-scale rows by dinv (fused in
//   GEMM epilogue), aggregate = plain neighbor sum, final scale by dinv[dst].
// Graph is materialized as CSR (by dst) each call: histogram -> scan -> fill.
// R1: GEMM retiled 64x64/4x4 -> 128x128/8x8 split-tile (LDS-BW-bound -> FMA-bound).

#define N_NODES 50000
#define BLK 256

// ---------------- CSR build ----------------
__global__ void k_indeg(const int* __restrict__ dst, int* __restrict__ indeg, int E) {
    int e = blockIdx.x * blockDim.x + threadIdx.x;
    if (e < E) atomicAdd(&indeg[dst[e]], 1);
}

#define SCAN_T 1024
__global__ void k_scan(const int* __restrict__ indeg, int* __restrict__ rowptr, int n) {
    __shared__ int sh[SCAN_T];
    __shared__ int s_carry;
    int tid = threadIdx.x;
    if (tid == 0) s_carry = 0;
    __syncthreads();
    const int CHUNK = SCAN_T * 8;
    for (int base = 0; base < n; base += CHUNK) {
        int loc[8]; int lsum = 0;
#pragma unroll
        for (int j = 0; j < 8; ++j) {
            int idx = base + tid * 8 + j;
            loc[j] = (idx < n) ? indeg[idx] : 0;
            lsum += loc[j];
        }
        sh[tid] = lsum;
        __syncthreads();
        for (int off = 1; off < SCAN_T; off <<= 1) {
            int t = (tid >= off) ? sh[tid - off] : 0;
            __syncthreads();
            sh[tid] += t;
            __syncthreads();
        }
        int excl = s_carry + sh[tid] - lsum;
        int total = s_carry + sh[SCAN_T - 1];
#pragma unroll
        for (int j = 0; j < 8; ++j) {
            int idx = base + tid * 8 + j;
            if (idx < n) rowptr[idx] = excl;
            excl += loc[j];
        }
        __syncthreads();
        if (tid == 0) s_carry = total;
        __syncthreads();
    }
    if (tid == 0) rowptr[n] = s_carry;
}

__global__ void k_fill(const int* __restrict__ src, const int* __restrict__ dst,
                       const int* __restrict__ rowptr, int* __restrict__ cursor,
                       int* __restrict__ col, int E) {
    int e = blockIdx.x * blockDim.x + threadIdx.x;
    if (e < E) {
        int d = dst[e];
        int pos = rowptr[d] + atomicAdd(&cursor[d], 1);
        col[pos] = src[e];
    }
}

__global__ void k_dinv(const int* __restrict__ indeg, float* __restrict__ dinv, int n) {
    int i = blockIdx.x * blockDim.x + threadIdx.x;
    if (i < n) dinv[i] = rsqrtf((float)indeg[i] + 1.0f);  // +1 = self loop
}

// xs[i] = emb[node_ids[i]] * dinv[i]   (128 feats, float4 lanes)
__global__ void k_prescale(const float* __restrict__ emb, const int* __restrict__ ids,
                           const float* __restrict__ dinv, float* __restrict__ xs, int n) {
    int t = blockIdx.x * blockDim.x + threadIdx.x;
    if (t >= n * 32) return;
    int node = t >> 5, lane = t & 31;
    int s = ids[node];
    float4 v = ((const float4*)emb)[(size_t)s * 32 + lane];
    float di = dinv[node];
    ((float4*)xs)[(size_t)node * 32 + lane] = make_float4(v.x*di, v.y*di, v.z*di, v.w*di);
}

// ---------------- aggregation ----------------
// out[i] = epi( dinv[i] * (H[i] + sum_{e: dst=i} H[col[e]]) )
// EPI 0: none; EPI 1: relu(. + bias)
template<int D, int EPI>
__global__ __launch_bounds__(BLK) void k_agg(const float* __restrict__ H,
        const int* __restrict__ rowptr, const int* __restrict__ col,
        const float* __restrict__ dinv, const float* __restrict__ bias,
        float* __restrict__ out, int n) {
    constexpr int LPN = D / 4;  // lanes per node (float4)
    int t = blockIdx.x * blockDim.x + threadIdx.x;
    int node = t / LPN;
    int lane = t % LPN;
    if (node >= n) return;
    const float4* Hv = (const float4*)H;
    float4 acc = Hv[(size_t)node * LPN + lane];   // self loop term
    int beg = rowptr[node], end = rowptr[node + 1];
    for (int e = beg; e < end; ++e) {
        int s = col[e];
        float4 v = Hv[(size_t)s * LPN + lane];
        acc.x += v.x; acc.y += v.y; acc.z += v.z; acc.w += v.w;
    }
    float di = dinv[node];
    float4 r;
    if constexpr (EPI == 0) {
        r = make_float4(acc.x*di, acc.y*di, acc.z*di, acc.w*di);
    } else {
        float4 b = ((const float4*)bias)[lane];
        r.x = fmaxf(fmaf(acc.x, di, b.x), 0.f);
        r.y = fmaxf(fmaf(acc.y, di, b.y), 0.f);
        r.z = fmaxf(fmaf(acc.z, di, b.z), 0.f);
        r.w = fmaxf(fmaf(acc.w, di, b.w), 0.f);
    }
    ((float4*)out)[(size_t)node * LPN + lane] = r;
}

// final layer: aggregate (128 feats) + bias + LayerNorm. one wave per node.
__global__ __launch_bounds__(BLK) void k_agg_ln(const float* __restrict__ H,
        const int* __restrict__ rowptr, const int* __restrict__ col,
        const float* __restrict__ dinv, const float* __restrict__ b3,
        const float* __restrict__ gamma, const float* __restrict__ beta,
        float* __restrict__ out, int n) {
    int gt = blockIdx.x * blockDim.x + threadIdx.x;
    int node = gt >> 6;
    int lane = gt & 63;
    if (node >= n) return;
    const float2* Hv = (const float2*)H;
    float2 acc = Hv[(size_t)node * 64 + lane];
    int beg = rowptr[node], end = rowptr[node + 1];
    for (int e = beg; e < end; ++e) {
        int s = col[e];
        float2 v = Hv[(size_t)s * 64 + lane];
        acc.x += v.x; acc.y += v.y;
    }
    float di = dinv[node];
    int f0 = lane * 2;
    float t0 = fmaf(acc.x, di, b3[f0]);
    float t1 = fmaf(acc.y, di, b3[f0 + 1]);
    float s = t0 + t1, sq = t0*t0 + t1*t1;
#pragma unroll
    for (int off = 32; off >= 1; off >>= 1) {
        s  += __shfl_xor(s, off, 64);
        sq += __shfl_xor(sq, off, 64);
    }
    float mu  = s * (1.0f / 128.0f);
    float var = sq * (1.0f / 128.0f) - mu * mu;
    float inv = rsqrtf(var + 1e-5f);
    float2 o;
    o.x = fmaf((t0 - mu) * inv, gamma[f0],     beta[f0]);
    o.y = fmaf((t1 - mu) * inv, gamma[f0 + 1], beta[f0 + 1]);
    ((float2*)out)[(size_t)node * 64 + lane] = o;
}

// ---------------- GEMM (fp32 vector, 128x128 tile, 8x8/thread split-tile) ----
// C[M,N] = A[M,K] @ B[K,N], epilogue:
//   EPI 0: relu(. + bias[col])        (layer1: after aggregation)
//   EPI 1: . * dinv[row]              (layers 2/3: pre-scale for aggregation)
// Thread (tx,ty) in 16x16 owns rows {ty*4..+3, 64+ty*4..+3} x cols
// {tx*4..+3, 64+tx*4..+3}. A-frag LDS reads are 4-address broadcasts (free);
// B-frag reads are 16 contiguous 16B requests = 2-way bank alias (free).
template<int EPI>
__global__ __launch_bounds__(256) void k_gemm(const float* __restrict__ A,
        const float* __restrict__ B, const float* __restrict__ bias,
        const float* __restrict__ dinv, float* __restrict__ C,
        int M, int N, int K) {
    constexpr int BM = 128, BN = 128, BK = 16;
    __shared__ float As[BK][BM];  // [k][m]
    __shared__ float Bs[BK][BN];  // [k][n]
    int m0 = blockIdx.x * BM;
    int n0 = blockIdx.y * BN;
    int tid = threadIdx.x;
    int tx = tid & 15, ty = tid >> 4;
    // A-load: thread -> rows {tid>>2, 64+(tid>>2)}, float4 kq = tid&3
    int ar  = tid >> 2;
    int akq = tid & 3;
    // B-load: thread -> k rows {tid>>5, 8+(tid>>5)}, float4 col = tid&31
    int bk  = tid >> 5;
    int bnc = tid & 31;
    float acc[8][8] = {};
    for (int k0 = 0; k0 < K; k0 += BK) {
#pragma unroll
        for (int h = 0; h < 2; ++h) {
            int row = ar + h * 64;
            int gm = m0 + row;
            float4 v = make_float4(0.f, 0.f, 0.f, 0.f);
            if (gm < M) v = *(const float4*)&A[(size_t)gm * K + k0 + akq * 4];
            As[akq*4+0][row] = v.x;
            As[akq*4+1][row] = v.y;
            As[akq*4+2][row] = v.z;
            As[akq*4+3][row] = v.w;
        }
#pragma unroll
        for (int h = 0; h < 2; ++h) {
            int kr = bk + h * 8;
            float4 v = *(const float4*)&B[(size_t)(k0 + kr) * N + n0 + bnc * 4];
            *(float4*)&Bs[kr][bnc * 4] = v;
        }
        __syncthreads();
#pragma unroll
        for (int kk = 0; kk < BK; ++kk) {
            float a[8], b[8];
            *(float4*)&a[0] = *(const float4*)&As[kk][ty * 4];
            *(float4*)&a[4] = *(const float4*)&As[kk][64 + ty * 4];
            *(float4*)&b[0] = *(const float4*)&Bs[kk][tx * 4];
            *(float4*)&b[4] = *(const float4*)&Bs[kk][64 + tx * 4];
#pragma unroll
            for (int i = 0; i < 8; ++i)
#pragma unroll
                for (int j = 0; j < 8; ++j)
                    acc[i][j] = fmaf(a[i], b[j], acc[i][j]);
        }
        __syncthreads();
    }
#pragma unroll
    for (int i = 0; i < 8; ++i) {
        int row = m0 + ((i < 4) ? (ty * 4 + i) : (64 + ty * 4 + i - 4));
        if (row >= M) continue;
        float sc = (EPI == 1) ? dinv[row] : 0.f;
#pragma unroll
        for (int h = 0; h < 2; ++h) {
            int c0 = n0 + h * 64 + tx * 4;
            const float* ac = &acc[i][h * 4];
            float4 o;
            if constexpr (EPI == 0) {
                o.x = fmaxf(ac[0] + bias[c0+0], 0.f);
                o.y = fmaxf(ac[1] + bias[c0+1], 0.f);
                o.z = fmaxf(ac[2] + bias[c0+2], 0.f);
                o.w = fmaxf(ac[3] + bias[c0+3], 0.f);
            } else {
                o = make_float4(ac[0]*sc, ac[1]*sc, ac[2]*sc, ac[3]*sc);
            }
            *(float4*)&C[(size_t)row * N + c0] = o;
        }
    }
}

static inline size_t align256(size_t x) { return (x + 255) & ~(size_t)255; }

extern "C" void kernel_launch(void* const* d_in, const int* in_sizes, int n_in,
                              void* d_out, int out_size, void* d_ws, size_t ws_size,
                              hipStream_t stream) {
    const int*   node_ids = (const int*)  d_in[0];
    const int*   ei       = (const int*)  d_in[1];
    const float* emb      = (const float*)d_in[2];
    const float* W1       = (const float*)d_in[3];
    const float* b1       = (const float*)d_in[4];
    const float* W2       = (const float*)d_in[5];
    const float* b2       = (const float*)d_in[6];
    const float* W3       = (const float*)d_in[7];
    const float* b3       = (const float*)d_in[8];
    const float* gamma    = (const float*)d_in[9];
    const float* beta     = (const float*)d_in[10];
    float* out = (float*)d_out;

    const int N = in_sizes[0];
    const int E = in_sizes[1] / 2;
    const int* esrc = ei;
    const int* edst = ei + E;

    // workspace carve-up
    char* p = (char*)d_ws;
    size_t off = 0;
    int*   indeg  = (int*)(p + off);  off = align256(off + (size_t)N * 4);
    int*   rowptr = (int*)(p + off);  off = align256(off + (size_t)(N + 1) * 4);
    int*   cursor = (int*)(p + off);  off = align256(off + (size_t)N * 4);
    float* dinv   = (float*)(p + off); off = align256(off + (size_t)N * 4);
    int*   col    = (int*)(p + off);  off = align256(off + (size_t)E * 4);
    float* bufC   = (float*)(p + off); off = align256(off + (size_t)N * 128 * 4); // xs / hs3
    float* bufA   = (float*)(p + off); off = align256(off + (size_t)N * 256 * 4); // xa / hs2
    float* bufB   = (float*)(p + off); off = align256(off + (size_t)N * 256 * 4); // x2 / x3

    hipMemsetAsync(indeg, 0, (size_t)N * 4, stream);
    hipMemsetAsync(cursor, 0, (size_t)N * 4, stream);

    int eb = (E + BLK - 1) / BLK;
    k_indeg<<<eb, BLK, 0, stream>>>(edst, indeg, E);
    k_scan<<<1, SCAN_T, 0, stream>>>(indeg, rowptr, N);
    k_fill<<<eb, BLK, 0, stream>>>(esrc, edst, rowptr, cursor, col, E);
    k_dinv<<<(N + BLK - 1) / BLK, BLK, 0, stream>>>(indeg, dinv, N);

    // layer 1: aggregate-first on 128 feats, then GEMM(+b1,relu)
    k_prescale<<<(N * 32 + BLK - 1) / BLK, BLK, 0, stream>>>(emb, node_ids, dinv, bufC, N);
    k_agg<128, 0><<<(N * 32 + BLK - 1) / BLK, BLK, 0, stream>>>(bufC, rowptr, col, dinv, nullptr, bufA, N);
    {
        dim3 g((N + 127) / 128, 256 / 128);
        k_gemm<0><<<g, 256, 0, stream>>>(bufA, W1, b1, nullptr, bufB, N, 256, 128);
    }
    // layer 2: GEMM(*dinv), aggregate(+b2,relu)
    {
        dim3 g((N + 127) / 128, 256 / 128);
        k_gemm<1><<<g, 256, 0, stream>>>(bufB, W2, nullptr, dinv, bufA, N, 256, 256);
    }
    k_agg<256, 1><<<(N * 64 + BLK - 1) / BLK, BLK, 0, stream>>>(bufA, rowptr, col, dinv, b2, bufB, N);
    // layer 3: GEMM(*dinv), aggregate+bias+LayerNorm
    {
        dim3 g((N + 127) / 128, 128 / 128);
        k_gemm<1><<<g, 256, 0, stream>>>(bufB, W3, nullptr, dinv, bufC, N, 128, 256);
    }
    k_agg_ln<<<(N * 64 + BLK - 1) / BLK, BLK, 0, stream>>>(bufC, rowptr, col, dinv, b3, gamma, beta, out, N);
}

// Round 3
// 586.200 us; speedup vs baseline: 1.2324x; 1.2324x over previous
//
#include <hip/hip_runtime.h>
#include <hip/hip_bf16.h>

// GCN: norm -> [agg,W1,relu] -> [W2,agg,relu] -> [W3,agg] -> LN
// R2: fp32 GEMM -> bf16 hi/lo 3-term MFMA GEMM (16x16x32), agg unroll-4,
//     shuffle-based scan. Inter-GEMM tensors carried as bf16 hi/lo pairs.

#define BLK 256

typedef __attribute__((ext_vector_type(8))) short bf16x8;
typedef __attribute__((ext_vector_type(4))) float f32x4;
typedef unsigned short u16;
typedef unsigned int u32;

__device__ inline u16 f2b_rne(float v) {
    u32 x = __float_as_uint(v);
    u32 r = (x + 0x7FFFu + ((x >> 16) & 1u)) >> 16;
    return (u16)r;
}
__device__ inline void split_bf(float v, u16& h, u16& l) {
    h = f2b_rne(v);
    float fh = __uint_as_float((u32)h << 16);
    l = f2b_rne(v - fh);
}

// ---------------- CSR build ----------------
__global__ void k_indeg(const int* __restrict__ dst, int* __restrict__ indeg, int E) {
    int e = blockIdx.x * blockDim.x + threadIdx.x;
    if (e < E) atomicAdd(&indeg[dst[e]], 1);
}

#define SCAN_T 1024
__global__ void k_scan(const int* __restrict__ indeg, int* __restrict__ rowptr, int n) {
    __shared__ int s_wsum[16];
    __shared__ int s_wpre[16];
    __shared__ int s_carry;
    int tid = threadIdx.x, lane = tid & 63, wid = tid >> 6;
    if (tid == 0) s_carry = 0;
    __syncthreads();
    const int CHUNK = SCAN_T * 8;
    for (int base = 0; base < n; base += CHUNK) {
        int idx0 = base + tid * 8;
        int loc[8]; int lsum = 0;
#pragma unroll
        for (int j = 0; j < 8; ++j) {
            int idx = idx0 + j;
            loc[j] = (idx < n) ? indeg[idx] : 0;
            lsum += loc[j];
        }
        int sc = lsum;  // inclusive wave scan
#pragma unroll
        for (int off = 1; off < 64; off <<= 1) {
            int t = __shfl_up(sc, off, 64);
            if (lane >= off) sc += t;
        }
        if (lane == 63) s_wsum[wid] = sc;
        __syncthreads();
        if (tid < 16) {
            int w = s_wsum[tid];
#pragma unroll
            for (int off = 1; off < 16; off <<= 1) {
                int t = __shfl_up(w, off, 64);
                if (tid >= off) w += t;
            }
            s_wpre[tid] = w;
        }
        __syncthreads();
        int excl = s_carry + (wid ? s_wpre[wid - 1] : 0) + sc - lsum;
#pragma unroll
        for (int j = 0; j < 8; ++j) {
            int idx = idx0 + j;
            if (idx < n) rowptr[idx] = excl;
            excl += loc[j];
        }
        __syncthreads();
        if (tid == 0) s_carry += s_wpre[15];
    }
    if (tid == 0) rowptr[n] = s_carry;
}

__global__ void k_fill(const int* __restrict__ src, const int* __restrict__ dst,
                       const int* __restrict__ rowptr, int* __restrict__ cursor,
                       int* __restrict__ col, int E) {
    int e = blockIdx.x * blockDim.x + threadIdx.x;
    if (e < E) {
        int d = dst[e];
        int pos = rowptr[d] + atomicAdd(&cursor[d], 1);
        col[pos] = src[e];
    }
}

__global__ void k_dinv(const int* __restrict__ indeg, float* __restrict__ dinv, int n) {
    int i = blockIdx.x * blockDim.x + threadIdx.x;
    if (i < n) dinv[i] = rsqrtf((float)indeg[i] + 1.0f);
}

// W[K][N] fp32 -> Wt[N][K] bf16 hi/lo
__global__ void k_wprep(const float* __restrict__ W, u16* __restrict__ Whi,
                        u16* __restrict__ Wlo, int K, int N) {
    int idx = blockIdx.x * blockDim.x + threadIdx.x;
    if (idx >= K * N) return;
    int nn = idx / K, kk = idx - nn * K;
    float v = W[(size_t)kk * N + nn];
    u16 h, l; split_bf(v, h, l);
    Whi[idx] = h; Wlo[idx] = l;
}

__global__ void k_prescale(const float* __restrict__ emb, const int* __restrict__ ids,
                           const float* __restrict__ dinv, float* __restrict__ xs, int n) {
    int t = blockIdx.x * blockDim.x + threadIdx.x;
    if (t >= n * 32) return;
    int node = t >> 5, lane = t & 31;
    int s = ids[node];
    float4 v = ((const float4*)emb)[(size_t)s * 32 + lane];
    float di = dinv[node];
    ((float4*)xs)[(size_t)node * 32 + lane] = make_float4(v.x*di, v.y*di, v.z*di, v.w*di);
}

// ---------------- aggregation (unroll-4, optional bf16 hi/lo output) -------
// out = epi( dinv[i] * (H[i] + sum_nb H) );  EPI0: *dinv  EPI1: relu(*dinv+b)
template<int D, int EPI, int OUT>
__global__ __launch_bounds__(BLK) void k_agg(const float* __restrict__ H,
        const int* __restrict__ rowptr, const int* __restrict__ col,
        const float* __restrict__ dinv, const float* __restrict__ bias,
        float* __restrict__ outf, u16* __restrict__ outh, u16* __restrict__ outl, int n) {
    constexpr int LPN = D / 4;
    int t = blockIdx.x * blockDim.x + threadIdx.x;
    int node = t / LPN;
    int lane = t % LPN;
    if (node >= n) return;
    const float4* Hv = (const float4*)H;
    float4 acc = Hv[(size_t)node * LPN + lane];
    int e = rowptr[node], end = rowptr[node + 1];
    for (; e + 4 <= end; e += 4) {
        int s0 = col[e], s1 = col[e+1], s2 = col[e+2], s3 = col[e+3];
        float4 v0 = Hv[(size_t)s0 * LPN + lane];
        float4 v1 = Hv[(size_t)s1 * LPN + lane];
        float4 v2 = Hv[(size_t)s2 * LPN + lane];
        float4 v3 = Hv[(size_t)s3 * LPN + lane];
        acc.x += (v0.x + v1.x) + (v2.x + v3.x);
        acc.y += (v0.y + v1.y) + (v2.y + v3.y);
        acc.z += (v0.z + v1.z) + (v2.z + v3.z);
        acc.w += (v0.w + v1.w) + (v2.w + v3.w);
    }
    for (; e < end; ++e) {
        int s = col[e];
        float4 v = Hv[(size_t)s * LPN + lane];
        acc.x += v.x; acc.y += v.y; acc.z += v.z; acc.w += v.w;
    }
    float di = dinv[node];
    float4 r;
    if constexpr (EPI == 0) {
        r = make_float4(acc.x*di, acc.y*di, acc.z*di, acc.w*di);
    } else {
        float4 b = ((const float4*)bias)[lane];
        r.x = fmaxf(fmaf(acc.x, di, b.x), 0.f);
        r.y = fmaxf(fmaf(acc.y, di, b.y), 0.f);
        r.z = fmaxf(fmaf(acc.z, di, b.z), 0.f);
        r.w = fmaxf(fmaf(acc.w, di, b.w), 0.f);
    }
    if constexpr (OUT == 0) {
        ((float4*)outf)[(size_t)node * LPN + lane] = r;
    } else {
        ushort4 h4, l4;
        split_bf(r.x, h4.x, l4.x);
        split_bf(r.y, h4.y, l4.y);
        split_bf(r.z, h4.z, l4.z);
        split_bf(r.w, h4.w, l4.w);
        ((ushort4*)outh)[(size_t)node * LPN + lane] = h4;
        ((ushort4*)outl)[(size_t)node * LPN + lane] = l4;
    }
}

// final: aggregate(128) + bias + LayerNorm; one wave per node
__global__ __launch_bounds__(BLK) void k_agg_ln(const float* __restrict__ H,
        const int* __restrict__ rowptr, const int* __restrict__ col,
        const float* __restrict__ dinv, const float* __restrict__ b3,
        const float* __restrict__ gamma, const float* __restrict__ beta,
        float* __restrict__ out, int n) {
    int gt = blockIdx.x * blockDim.x + threadIdx.x;
    int node = gt >> 6;
    int lane = gt & 63;
    if (node >= n) return;
    const float2* Hv = (const float2*)H;
    float2 acc = Hv[(size_t)node * 64 + lane];
    int e = rowptr[node], end = rowptr[node + 1];
    for (; e + 4 <= end; e += 4) {
        int s0 = col[e], s1 = col[e+1], s2 = col[e+2], s3 = col[e+3];
        float2 v0 = Hv[(size_t)s0 * 64 + lane];
        float2 v1 = Hv[(size_t)s1 * 64 + lane];
        float2 v2 = Hv[(size_t)s2 * 64 + lane];
        float2 v3 = Hv[(size_t)s3 * 64 + lane];
        acc.x += (v0.x + v1.x) + (v2.x + v3.x);
        acc.y += (v0.y + v1.y) + (v2.y + v3.y);
    }
    for (; e < end; ++e) {
        int s = col[e];
        float2 v = Hv[(size_t)s * 64 + lane];
        acc.x += v.x; acc.y += v.y;
    }
    float di = dinv[node];
    int f0 = lane * 2;
    float t0 = fmaf(acc.x, di, b3[f0]);
    float t1 = fmaf(acc.y, di, b3[f0 + 1]);
    float s = t0 + t1, sq = t0*t0 + t1*t1;
#pragma unroll
    for (int off = 32; off >= 1; off >>= 1) {
        s  += __shfl_xor(s, off, 64);
        sq += __shfl_xor(sq, off, 64);
    }
    float mu  = s * (1.0f / 128.0f);
    float var = sq * (1.0f / 128.0f) - mu * mu;
    float inv = rsqrtf(var + 1e-5f);
    float2 o;
    o.x = fmaf((t0 - mu) * inv, gamma[f0],     beta[f0]);
    o.y = fmaf((t1 - mu) * inv, gamma[f0 + 1], beta[f0 + 1]);
    ((float2*)out)[(size_t)node * 64 + lane] = o;
}

// ---------------- bf16x3 MFMA GEMM -----------------------------------------
// C = (Ahi+Alo)@(Bhi+Blo) ~= Ahi@Bhi + Ahi@Blo + Alo@Bhi   (err ~2^-16)
// A: [M][K] bf16 pair; B: Wt [N][K] bf16 pair (pre-transposed).
// Tile 128x128, BK=64, 4 waves x (64x64 = 4x4 frags of 16x16x32).
// LDS tiles [row][slot 16B], XOR-swizzled slot^=(row&7) on write AND read.
// EPI 0: relu(x + bias[n]) -> bf16 hi/lo out.  EPI 1: x*dinv[m] -> fp32 out.
template<int EPI>
__global__ __launch_bounds__(256) void k_gemm_bf3(
        const u16* __restrict__ Ahi, const u16* __restrict__ Alo,
        const u16* __restrict__ Bhi, const u16* __restrict__ Blo,
        const float* __restrict__ bias, const float* __restrict__ dinv,
        float* __restrict__ Cf, u16* __restrict__ Chi, u16* __restrict__ Clo,
        int M, int N, int K) {
    __shared__ u16 sA[2][128 * 64];
    __shared__ u16 sB[2][128 * 64];
    int m0 = blockIdx.x * 128;
    int n0 = blockIdx.y * 128;
    int tid = threadIdx.x;
    int lane = tid & 63, wid = tid >> 6;
    int wm = wid >> 1, wn = wid & 1;
    int r16 = lane & 15, kg = lane >> 4;
    f32x4 acc[4][4] = {};
    for (int k0 = 0; k0 < K; k0 += 64) {
        for (int c = tid; c < 1024; c += 256) {
            int row = c >> 3, slot = c & 7;
            int sl = slot ^ (row & 7);
            int gm = m0 + row;
            uint4 vh = make_uint4(0u,0u,0u,0u), vl = vh;
            if (gm < M) {
                size_t g = (size_t)gm * K + k0 + slot * 8;
                vh = *(const uint4*)(Ahi + g);
                vl = *(const uint4*)(Alo + g);
            }
            *(uint4*)&sA[0][row * 64 + sl * 8] = vh;
            *(uint4*)&sA[1][row * 64 + sl * 8] = vl;
            size_t gb = (size_t)(n0 + row) * K + k0 + slot * 8;
            *(uint4*)&sB[0][row * 64 + sl * 8] = *(const uint4*)(Bhi + gb);
            *(uint4*)&sB[1][row * 64 + sl * 8] = *(const uint4*)(Blo + gb);
        }
        __syncthreads();
#pragma unroll
        for (int kk = 0; kk < 2; ++kk) {
            bf16x8 ah[4], al[4], bh[4], bl[4];
#pragma unroll
            for (int f = 0; f < 4; ++f) {
                int ar = wm * 64 + f * 16 + r16;
                int asl = (kk * 4 + kg) ^ (ar & 7);
                ah[f] = *(const bf16x8*)&sA[0][ar * 64 + asl * 8];
                al[f] = *(const bf16x8*)&sA[1][ar * 64 + asl * 8];
                int br = wn * 64 + f * 16 + r16;
                int bsl = (kk * 4 + kg) ^ (br & 7);
                bh[f] = *(const bf16x8*)&sB[0][br * 64 + bsl * 8];
                bl[f] = *(const bf16x8*)&sB[1][br * 64 + bsl * 8];
            }
#pragma unroll
            for (int i = 0; i < 4; ++i)
#pragma unroll
            for (int j = 0; j < 4; ++j) {
                acc[i][j] = __builtin_amdgcn_mfma_f32_16x16x32_bf16(ah[i], bh[j], acc[i][j], 0, 0, 0);
                acc[i][j] = __builtin_amdgcn_mfma_f32_16x16x32_bf16(ah[i], bl[j], acc[i][j], 0, 0, 0);
                acc[i][j] = __builtin_amdgcn_mfma_f32_16x16x32_bf16(al[i], bh[j], acc[i][j], 0, 0, 0);
            }
        }
        __syncthreads();
    }
    // epilogue: C/D layout col=lane&15, row=(lane>>4)*4+reg  [m89-verified]
#pragma unroll
    for (int i = 0; i < 4; ++i) {
#pragma unroll
        for (int j = 0; j < 4; ++j) {
            int nn = n0 + wn * 64 + j * 16 + r16;
            float bv = 0.f;
            if constexpr (EPI == 0) bv = bias[nn];
#pragma unroll
            for (int r = 0; r < 4; ++r) {
                int mm = m0 + wm * 64 + i * 16 + kg * 4 + r;
                if (mm >= M) continue;
                float x = acc[i][j][r];
                if constexpr (EPI == 0) {
                    x = fmaxf(x + bv, 0.f);
                    u16 h, l; split_bf(x, h, l);
                    size_t o = (size_t)mm * N + nn;
                    Chi[o] = h; Clo[o] = l;
                } else {
                    x *= dinv[mm];
                    Cf[(size_t)mm * N + nn] = x;
                }
            }
        }
    }
}

static inline size_t align256(size_t x) { return (x + 255) & ~(size_t)255; }

extern "C" void kernel_launch(void* const* d_in, const int* in_sizes, int n_in,
                              void* d_out, int out_size, void* d_ws, size_t ws_size,
                              hipStream_t stream) {
    const int*   node_ids = (const int*)  d_in[0];
    const int*   ei       = (const int*)  d_in[1];
    const float* emb      = (const float*)d_in[2];
    const float* W1       = (const float*)d_in[3];
    const float* b1       = (const float*)d_in[4];
    const float* W2       = (const float*)d_in[5];
    const float* b2       = (const float*)d_in[6];
    const float* W3       = (const float*)d_in[7];
    const float* b3       = (const float*)d_in[8];
    const float* gamma    = (const float*)d_in[9];
    const float* beta     = (const float*)d_in[10];
    float* out = (float*)d_out;

    const int N = in_sizes[0];
    const int E = in_sizes[1] / 2;
    const int* esrc = ei;
    const int* edst = ei + E;

    char* p = (char*)d_ws;
    size_t off = 0;
    int*   indeg  = (int*)(p + off);   off = align256(off + (size_t)N * 4);
    int*   rowptr = (int*)(p + off);   off = align256(off + (size_t)(N + 1) * 4);
    int*   cursor = (int*)(p + off);   off = align256(off + (size_t)N * 4);
    float* dinv   = (float*)(p + off); off = align256(off + (size_t)N * 4);
    int*   col    = (int*)(p + off);   off = align256(off + (size_t)E * 4);
    u16* W1thi = (u16*)(p + off); off = align256(off + 256 * 128 * 2);
    u16* W1tlo = (u16*)(p + off); off = align256(off + 256 * 128 * 2);
    u16* W2thi = (u16*)(p + off); off = align256(off + 256 * 256 * 2);
    u16* W2tlo = (u16*)(p + off); off = align256(off + 256 * 256 * 2);
    u16* W3thi = (u16*)(p + off); off = align256(off + 128 * 256 * 2);
    u16* W3tlo = (u16*)(p + off); off = align256(off + 128 * 256 * 2);
    char* S1 = p + off; off = align256(off + (size_t)N * 256 * 4);
    char* S2 = p + off; off = align256(off + (size_t)N * 256 * 4);

    // S1: X fp32 [N*128] -> H1 hi/lo [N*256 each] -> X2 hi/lo
    // S2: A1 hi/lo [N*128 each] -> G2 fp32 [N*256] -> G3 fp32 [N*128]
    float* X    = (float*)S1;
    u16*   H1hi = (u16*)S1;
    u16*   H1lo = (u16*)(S1 + (size_t)N * 256 * 2);
    u16*   X2hi = H1hi;
    u16*   X2lo = H1lo;
    u16*   A1hi = (u16*)S2;
    u16*   A1lo = (u16*)(S2 + (size_t)N * 128 * 2);
    float* G2   = (float*)S2;
    float* G3   = (float*)S2;

    hipMemsetAsync(indeg, 0, (size_t)N * 4, stream);
    hipMemsetAsync(cursor, 0, (size_t)N * 4, stream);

    int eb = (E + BLK - 1) / BLK;
    k_indeg<<<eb, BLK, 0, stream>>>(edst, indeg, E);
    k_scan<<<1, SCAN_T, 0, stream>>>(indeg, rowptr, N);
    k_fill<<<eb, BLK, 0, stream>>>(esrc, edst, rowptr, cursor, col, E);
    k_dinv<<<(N + BLK - 1) / BLK, BLK, 0, stream>>>(indeg, dinv, N);

    k_wprep<<<(128 * 256 + 255) / 256, 256, 0, stream>>>(W1, W1thi, W1tlo, 128, 256);
    k_wprep<<<(256 * 256 + 255) / 256, 256, 0, stream>>>(W2, W2thi, W2tlo, 256, 256);
    k_wprep<<<(256 * 128 + 255) / 256, 256, 0, stream>>>(W3, W3thi, W3tlo, 256, 128);

    int mg = (N + 127) / 128;

    k_prescale<<<(N * 32 + BLK - 1) / BLK, BLK, 0, stream>>>(emb, node_ids, dinv, X, N);
    k_agg<128, 0, 1><<<(N * 32 + BLK - 1) / BLK, BLK, 0, stream>>>(
        X, rowptr, col, dinv, nullptr, nullptr, A1hi, A1lo, N);
    k_gemm_bf3<0><<<dim3(mg, 2), 256, 0, stream>>>(
        A1hi, A1lo, W1thi, W1tlo, b1, nullptr, nullptr, H1hi, H1lo, N, 256, 128);
    k_gemm_bf3<1><<<dim3(mg, 2), 256, 0, stream>>>(
        H1hi, H1lo, W2thi, W2tlo, nullptr, dinv, G2, nullptr, nullptr, N, 256, 256);
    k_agg<256, 1, 1><<<(N * 64 + BLK - 1) / BLK, BLK, 0, stream>>>(
        G2, rowptr, col, dinv, b2, nullptr, X2hi, X2lo, N);
    k_gemm_bf3<1><<<dim3(mg, 1), 256, 0, stream>>>(
        X2hi, X2lo, W3thi, W3tlo, nullptr, dinv, G3, nullptr, nullptr, N, 128, 256);
    k_agg_ln<<<(N * 64 + BLK - 1) / BLK, BLK, 0, stream>>>(
        G3, rowptr, col, dinv, b3, gamma, beta, out, N);
}